// Round 1
// baseline (243.381 us; speedup 1.0000x reference)
//
#include <hip/hip_runtime.h>
#include <math.h>

// ECT layer: ect[b,t,r] = sum_{n: batch[n]==b} sigmoid(8*(lin[r] - <x_n, v_t>))
// N=100000, D=3, T=64, R=64, B=128, lin = linspace(-1.1, 1.1, 64).
//
// Strategy: VALU-bound problem (4.1e8 sigmoids, ~4MB total HBM traffic).
// - Each block processes NPB consecutive nodes (batch is sorted).
// - 256 threads: thread owns (t = tid>>2, r in [16*(tid&3), +16)) -> the full
//   64x64 (t,r) tile lives in per-thread register accumulators (16 floats).
// - Per node: nh = <x,v_t> once; exp recurrence over r: e_r = e0 * k^j with
//   k = exp(-8*dlin) const -> ONE v_exp per 16 r's, then
//   acc[j] += v_rcp(fma(e0, k^j, 1)). Saturation (e0 -> 0 or inf) is exact.
// - Flush to global via atomicAdd only at (wave-uniform) batch boundaries and
//   block end. d_out zeroed via hipMemsetAsync each call (harness poisons it).

#define NPB 128
#define THREADS 256

#if __has_builtin(__builtin_amdgcn_exp2f)
#define EXP2F(x) __builtin_amdgcn_exp2f(x)
#else
#define EXP2F(x) exp2f(x)
#endif
#if __has_builtin(__builtin_amdgcn_rcpf)
#define RCPF(x) __builtin_amdgcn_rcpf(x)
#else
#define RCPF(x) (1.0f / (x))
#endif

__global__ __launch_bounds__(THREADS) void ECTLayer_kernel(
    const float* __restrict__ x,      // [N,3] row-major
    const float* __restrict__ v,      // [3,64] row-major
    const int*   __restrict__ batch,  // [N] sorted, 0..127
    float* __restrict__ out,          // [128,64,64]
    int n, float kmul)                // kmul = exp(-8*2.2/63)
{
    __shared__ float sx[NPB * 3];
    __shared__ int   sb[NPB];

    const int tid  = threadIdx.x;
    const int base = blockIdx.x * NPB;
    const int cnt  = min(NPB, n - base);

    for (int i = tid; i < cnt * 3; i += THREADS) sx[i] = x[base * 3 + i];
    for (int i = tid; i < cnt; i += THREADS)     sb[i] = batch[base + i];
    __syncthreads();

    const int t  = tid >> 2;       // direction index 0..63
    const int rg = tid & 3;        // r-group: r = rg*16 .. rg*16+15
    const float v0 = v[t], v1 = v[64 + t], v2 = v[128 + t];

    const float C2   = 11.541560327111707f;              // 8 * log2(e)
    const float lin0 = -1.1f + (float)(rg * 16) * (2.2f / 63.0f);
    const float u0   = -lin0 * C2;

    float kp[16], acc[16];
    kp[0] = 1.0f;
#pragma unroll
    for (int j = 1; j < 16; ++j) kp[j] = kp[j - 1] * kmul;
#pragma unroll
    for (int j = 0; j < 16; ++j) acc[j] = 0.0f;

    int cur_b = sb[0];
    for (int i = 0; i < cnt; ++i) {
        const int b = sb[i];               // wave-uniform (LDS broadcast)
        if (b != cur_b) {                  // rare: ~127 boundaries total
            float* dst = out + ((size_t)cur_b * 64 + t) * 64 + rg * 16;
#pragma unroll
            for (int j = 0; j < 16; ++j) { atomicAdd(dst + j, acc[j]); acc[j] = 0.0f; }
            cur_b = b;
        }
        const float x0 = sx[i * 3], x1 = sx[i * 3 + 1], x2 = sx[i * 3 + 2];
        const float nh = fmaf(x0, v0, fmaf(x1, v1, x2 * v2));
        const float e0 = EXP2F(fmaf(nh, C2, u0));   // exp(8*(nh - lin[rg*16]))
#pragma unroll
        for (int j = 0; j < 16; ++j)
            acc[j] += RCPF(fmaf(e0, kp[j], 1.0f));  // sigmoid(8*(lin[r]-nh))
    }
    float* dst = out + ((size_t)cur_b * 64 + t) * 64 + rg * 16;
#pragma unroll
    for (int j = 0; j < 16; ++j) atomicAdd(dst + j, acc[j]);
}

extern "C" void kernel_launch(void* const* d_in, const int* in_sizes, int n_in,
                              void* d_out, int out_size, void* d_ws, size_t ws_size,
                              hipStream_t stream) {
    const float* x     = (const float*)d_in[0];
    const float* v     = (const float*)d_in[1];
    const int*   batch = (const int*)d_in[2];
    float*       out   = (float*)d_out;

    const int n = in_sizes[0] / 3;  // N nodes

    // Output is accumulated via atomics; harness poisons d_out and does not
    // re-zero between replays -> zero it every call (capture-safe memset).
    hipMemsetAsync(d_out, 0, (size_t)out_size * sizeof(float), stream);

    const float kmul = (float)exp(-8.0 * 2.2 / 63.0);  // per-r exp ratio
    const int nblocks = (n + NPB - 1) / NPB;
    hipLaunchKernelGGL(ECTLayer_kernel, dim3(nblocks), dim3(THREADS), 0, stream,
                       x, v, batch, out, n, kmul);
}